// Round 14
// baseline (374.670 us; speedup 1.0000x reference)
//
#include <hip/hip_runtime.h>

typedef float f32x4 __attribute__((ext_vector_type(4)));
typedef short bfrag __attribute__((ext_vector_type(8)));
typedef short s16x8 __attribute__((ext_vector_type(8)));
typedef unsigned short u16;

__device__ __forceinline__ u16 f2bf(float f) {
  union { float f; unsigned u; } x; x.f = f;
  unsigned r = x.u + 0x7fffu + ((x.u >> 16) & 1u);
  return (u16)(r >> 16);
}
__device__ __forceinline__ float bf2f(u16 v) {
  union { unsigned u; float f; } x; x.u = ((unsigned)v) << 16;
  return x.f;
}

__device__ __forceinline__ void g2l16(const void* g, void* l) {
  void* gnc = const_cast<void*>(g);
  __builtin_amdgcn_global_load_lds((__attribute__((address_space(1))) void*)gnc,
                                   (__attribute__((address_space(3))) void*)l, 16, 0, 0);
}

__device__ __forceinline__ f32x4 mfma16(bfrag a, bfrag b, f32x4 c) {
  asm volatile("v_mfma_f32_16x16x32_bf16 %0, %1, %2, %0" : "+v"(c) : "v"(a), "v"(b));
  return c;
}

__device__ __forceinline__ float wred_sum(float s) {
  #pragma unroll
  for (int o = 32; o; o >>= 1) s += __shfl_xor(s, o);
  return s;
}

__device__ __forceinline__ float gelu_f(float v) {
  return 0.5f * v * (1.f + erff(v * 0.70710678118f));
}

// ---------------- fused f32 -> bf16 convert (12 weight tensors) ----------------
struct CvtArgs {
  const float* s[12];
  u16* d[12];
  int eb[12];
};

__global__ __launch_bounds__(256) void cvt_all(CvtArgs a) {
  const int blk = blockIdx.x;
  int base = 0;
  const float* sp = a.s[0];
  u16* dp = a.d[0];
  #pragma unroll
  for (int i = 0; i < 11; ++i) {
    if (blk >= a.eb[i]) { base = a.eb[i]; sp = a.s[i + 1]; dp = a.d[i + 1]; }
  }
  const size_t gi = ((size_t)(blk - base) * 256 + threadIdx.x) * 4;
  float4 f = *(const float4*)(sp + gi);
  ushort4 o;
  o.x = f2bf(f.x); o.y = f2bf(f.y); o.z = f2bf(f.z); o.w = f2bf(f.w);
  *(ushort4*)(dp + gi) = o;
}

// ---------------- bias concat ----------------
__global__ __launch_bounds__(512) void biascat_k(
    const float* __restrict__ bkp, const float* __restrict__ bvp,
    const float* __restrict__ bqp, const float* __restrict__ bkd,
    const float* __restrict__ bvd, float* __restrict__ bp3,
    float* __restrict__ bd2) {
  int t = threadIdx.x;
  bp3[t] = bkp[t];
  bp3[512 + t] = bvp[t];
  bp3[1024 + t] = bqp[t];
  bd2[t] = bkd[t];
  bd2[512 + t] = bvd[t];
}

// ---------------- uncertainty gates + h -> bf16 emit ----------------
__device__ __forceinline__ float softplus_s(float x) {
  return fmaxf(x, 0.f) + log1pf(expf(-fabsf(x)));
}

__global__ __launch_bounds__(256) void gate_k(
    const float* __restrict__ hd, const float* __restrict__ hp,
    const float* __restrict__ wd, const float* __restrict__ bd,
    const float* __restrict__ wp, const float* __restrict__ bp,
    float* __restrict__ lgd, float* __restrict__ lgp,
    u16* __restrict__ hd16, u16* __restrict__ hp16, int mdTok) {
  const int lane = threadIdx.x & 63, wv = threadIdx.x >> 6;
  size_t tok = (size_t)blockIdx.x * 4 + wv;
  const float* h; const float* w4; const float* b4; float* lg; u16* ho;
  if (tok < (size_t)mdTok) { h = hd; w4 = wd; b4 = bd; lg = lgd; ho = hd16; }
  else { h = hp; w4 = wp; b4 = bp; lg = lgp; ho = hp16; tok -= mdTok; }
  const float* x = h + tok * 512;
  u16* xo = ho + tok * 512;
  float s0 = 0.f, s1 = 0.f, s2 = 0.f, s3 = 0.f;
  #pragma unroll
  for (int i = 0; i < 8; ++i) {
    int c = (i << 6) + lane;
    float xv = x[c];
    xo[c] = f2bf(xv);
    s0 += xv * w4[c];
    s1 += xv * w4[512 + c];
    s2 += xv * w4[1024 + c];
    s3 += xv * w4[1536 + c];
  }
  s0 = wred_sum(s0); s1 = wred_sum(s1); s2 = wred_sum(s2); s3 = wred_sum(s3);
  if (lane == 0) {
    float mu = s0 + b4[0];
    float va = softplus_s(s1 + b4[1]) + 1e-6f;
    float al = softplus_s(s2 + b4[2]) + 1.f + 1e-6f;
    float be = softplus_s(s3 + b4[3]) + 1e-6f;
    float se2 = be / (va * (al - 1.f));
    float g = (1.f / (1.f + expf(-mu))) * expf(-se2);
    g = fminf(fmaxf(g, 1e-3f), 1.f);
    lg[tok] = logf(g + 1e-9f);
  }
}

// ---------------- residual(bf16) + LayerNorm ----------------
__device__ __forceinline__ void ln_body(const u16* res, const u16* y,
                                        const float* sc, const float* bi,
                                        void* outv, int fp32out, size_t row,
                                        int lane) {
  const int c0 = lane * 8;
  float v[8];
  s16x8 yv = *(const s16x8*)(y + row * 512 + c0);
  s16x8 rv = *(const s16x8*)(res + row * 512 + c0);
  float s = 0.f;
  #pragma unroll
  for (int i = 0; i < 8; ++i) {
    v[i] = bf2f((u16)rv[i]) + bf2f((u16)yv[i]);
    s += v[i];
  }
  s = wred_sum(s);
  float m = s * (1.f / 512.f);
  float s2 = 0.f;
  #pragma unroll
  for (int i = 0; i < 8; ++i) { float d = v[i] - m; s2 += d * d; }
  s2 = wred_sum(s2);
  float inv = rsqrtf(s2 * (1.f / 512.f) + 1e-5f);
  float4 sc0 = *(const float4*)(sc + c0), sc1 = *(const float4*)(sc + c0 + 4);
  float4 bi0 = *(const float4*)(bi + c0), bi1 = *(const float4*)(bi + c0 + 4);
  float scv[8] = {sc0.x, sc0.y, sc0.z, sc0.w, sc1.x, sc1.y, sc1.z, sc1.w};
  float biv[8] = {bi0.x, bi0.y, bi0.z, bi0.w, bi1.x, bi1.y, bi1.z, bi1.w};
  float o[8];
  #pragma unroll
  for (int i = 0; i < 8; ++i) o[i] = (v[i] - m) * inv * scv[i] + biv[i];
  if (fp32out) {
    float* of = (float*)outv + row * 512 + c0;
    *(float4*)of = float4{o[0], o[1], o[2], o[3]};
    *(float4*)(of + 4) = float4{o[4], o[5], o[6], o[7]};
  } else {
    s16x8 ov;
    #pragma unroll
    for (int i = 0; i < 8; ++i) ov[i] = (short)f2bf(o[i]);
    *(s16x8*)((u16*)outv + row * 512 + c0) = ov;
  }
}

__global__ __launch_bounds__(256) void ln_k(const u16* __restrict__ res,
                                            const u16* __restrict__ y,
                                            const float* __restrict__ sc,
                                            const float* __restrict__ bi,
                                            u16* __restrict__ out) {
  const int lane = threadIdx.x & 63, w = threadIdx.x >> 6;
  const size_t row = (size_t)blockIdx.x * 4 + w;
  ln_body(res, y, sc, bi, out, 0, row, lane);
}

__global__ __launch_bounds__(256) void lnf_k(
    const u16* __restrict__ rd, const u16* __restrict__ yd,
    const float* __restrict__ scd, const float* __restrict__ bid,
    float* __restrict__ od,
    const u16* __restrict__ rp, const u16* __restrict__ yp,
    const float* __restrict__ scp, const float* __restrict__ bip,
    float* __restrict__ op, int mdRows) {
  const int lane = threadIdx.x & 63, w = threadIdx.x >> 6;
  size_t row = (size_t)blockIdx.x * 4 + w;
  if (row < (size_t)mdRows)
    ln_body(rd, yd, scd, bid, od, 1, row, lane);
  else
    ln_body(rp, yp, scp, bip, op, 1, row - mdRows, lane);
}

// ---------------- fused flash cross-attention (Out may alias Q: per-block disjoint) ----------------
template <int KT>
__global__ __launch_bounds__(256) void flash_k(
    const u16* __restrict__ Q, const u16* __restrict__ Kv,
    const u16* __restrict__ Vt, const float* __restrict__ logg,
    const int* __restrict__ mask, u16* __restrict__ Out,
    int Lq, int Lk, float scale) {
  __shared__ __align__(16) u16 Kl[KT * 64];
  __shared__ __align__(16) u16 Vl[64 * KT];
  __shared__ __align__(16) u16 Pl[64 * (KT + 8)];
  const int tid = threadIdx.x;
  const int lane = tid & 63, wv = tid >> 6;
  const int lr = lane & 15, lg4 = lane >> 4;
  const int bh = blockIdx.z;
  const int b = bh >> 3, h = bh & 7;
  const int q0 = blockIdx.x * 64;

  bfrag af[2];
  {
    const u16* qrow = Q + (size_t)(b * Lq + q0 + wv * 16 + lr) * 512 + h * 64;
    af[0] = *(const bfrag*)(qrow + lg4 * 8);
    af[1] = *(const bfrag*)(qrow + 32 + lg4 * 8);
  }
  float mreg[4] = {-3e38f, -3e38f, -3e38f, -3e38f};
  float lreg[4] = {0.f, 0.f, 0.f, 0.f};
  f32x4 Oa[4] = {};
  const float* lgb = logg + (size_t)b * Lk;
  const int* mkb = mask + (size_t)b * Lk;

  const int NKT = Lk / KT;
  for (int t = 0; t < NKT; ++t) {
    const int k0 = t * KT;
    __syncthreads();
    {
      const char* kb = (const char*)(Kv + (size_t)(b * Lk + k0) * 512 + h * 64);
      #pragma unroll
      for (int r = 0; r < KT / 32; ++r) {
        int o = r * 4096 + tid * 16;
        int rr = o >> 7, cd = (o >> 4) & 7;
        int cs = cd ^ (rr & 7);
        g2l16(kb + (size_t)rr * 1024 + cs * 16, (char*)Kl + o);
      }
      const char* vb = (const char*)(Vt + (size_t)bh * 64 * Lk + k0);
      #pragma unroll
      for (int r = 0; r < KT / 32; ++r) {
        int o = r * 4096 + tid * 16;
        int rr = o >> 8, cd = (o >> 4) & 15;
        int cs = (cd & 8) | ((cd & 7) ^ (rr & 7));
        g2l16(vb + (size_t)rr * (Lk * 2) + cs * 16, (char*)Vl + o);
      }
    }
    __syncthreads();

    f32x4 sa[KT / 16];
    #pragma unroll
    for (int n = 0; n < KT / 16; ++n) {
      sa[n] = f32x4{0.f, 0.f, 0.f, 0.f};
      int row = n * 16 + lr;
      #pragma unroll
      for (int ks = 0; ks < 2; ++ks) {
        bfrag kf = *(const bfrag*)(Kl + row * 64 + (((ks * 4 + lg4) ^ (row & 7)) * 8));
        sa[n] = mfma16(af[ks], kf, sa[n]);
      }
    }
    asm volatile("s_nop 7\n\ts_nop 7");

    float pv[KT / 16][4];
    float nm[4] = {-3e38f, -3e38f, -3e38f, -3e38f};
    #pragma unroll
    for (int n = 0; n < KT / 16; ++n) {
      int kk = k0 + n * 16 + lr;
      float lgv = lgb[kk];
      int mkv = mkb[kk];
      #pragma unroll
      for (int e = 0; e < 4; ++e) {
        float tv = mkv ? fmaf(sa[n][e], scale, lgv) : -1e9f;
        pv[n][e] = tv;
        nm[e] = fmaxf(nm[e], tv);
      }
    }
    float fac[4], rs[4];
    #pragma unroll
    for (int e = 0; e < 4; ++e) {
      nm[e] = fmaxf(nm[e], __shfl_xor(nm[e], 1));
      nm[e] = fmaxf(nm[e], __shfl_xor(nm[e], 2));
      nm[e] = fmaxf(nm[e], __shfl_xor(nm[e], 4));
      nm[e] = fmaxf(nm[e], __shfl_xor(nm[e], 8));
      nm[e] = fmaxf(nm[e], mreg[e]);
      fac[e] = __expf(mreg[e] - nm[e]);
      mreg[e] = nm[e];
      rs[e] = 0.f;
    }
    #pragma unroll
    for (int n = 0; n < KT / 16; ++n)
      #pragma unroll
      for (int e = 0; e < 4; ++e) {
        float p = __expf(pv[n][e] - nm[e]);
        pv[n][e] = p;
        rs[e] += p;
      }
    #pragma unroll
    for (int e = 0; e < 4; ++e) {
      rs[e] += __shfl_xor(rs[e], 1);
      rs[e] += __shfl_xor(rs[e], 2);
      rs[e] += __shfl_xor(rs[e], 4);
      rs[e] += __shfl_xor(rs[e], 8);
      lreg[e] = lreg[e] * fac[e] + rs[e];
    }
    #pragma unroll
    for (int n2 = 0; n2 < 4; ++n2)
      #pragma unroll
      for (int e = 0; e < 4; ++e) Oa[n2][e] *= fac[e];

    {
      int prow = wv * 16 + lg4 * 4;
      #pragma unroll
      for (int n = 0; n < KT / 16; ++n)
        #pragma unroll
        for (int e = 0; e < 4; ++e)
          Pl[(prow + e) * (KT + 8) + n * 16 + lr] = f2bf(pv[n][e]);
    }
    #pragma unroll
    for (int ks = 0; ks < KT / 32; ++ks) {
      bfrag pf = *(const bfrag*)(Pl + (wv * 16 + lr) * (KT + 8) + (ks * 4 + lg4) * 8);
      #pragma unroll
      for (int n2 = 0; n2 < 4; ++n2) {
        int vrow = n2 * 16 + lr;
        int ch = ks * 4 + lg4;
        int chs = (ch & 8) | ((ch & 7) ^ (vrow & 7));
        bfrag vf = *(const bfrag*)(Vl + vrow * KT + chs * 8);
        Oa[n2] = mfma16(pf, vf, Oa[n2]);
      }
    }
  }
  asm volatile("s_nop 7\n\ts_nop 7");

  float inv[4];
  #pragma unroll
  for (int e = 0; e < 4; ++e) inv[e] = 1.f / lreg[e];
  u16* ob = Out + (size_t)(b * Lq + q0 + wv * 16 + lg4 * 4) * 512 + h * 64;
  #pragma unroll
  for (int n2 = 0; n2 < 4; ++n2)
    #pragma unroll
    for (int e = 0; e < 4; ++e)
      ob[(size_t)e * 512 + n2 * 16 + lr] = f2bf(Oa[n2][e] * inv[e]);
}

// ---------------- m97-exact 128x128/BK=32 MFMA GEMM (16 KB LDS), 2-descriptor ----------------
// Single variable changed vs R13: BK 64 -> 32. 2 g2l16/thread/matrix per K-step,
// 16 MFMA per K-step, ~8 blocks/CU occupancy. Same-K merges + per-descriptor swizzle.
// epi: 1=bf16, 2=gelu->bf16,
//      4=kvq concat: c<512 -> C (ld512); c<1024 -> V^T C2 (TR); else C3 (ld512)
//      5=kd|vd concat: c<512 -> C; else V^T -> C2
struct GemmDesc {
  const u16* A;
  const u16* W;
  const float* bias;
  u16 *C, *C2, *C3;
  int K, lda, ldw, ldc, NB, TR, epi, nblocks;
};

__device__ __forceinline__ int xcdswz(int wg, int nb) {
  int xcd = wg & 7, idx = wg >> 3, q = nb >> 3, r = nb & 7;
  return (xcd < r ? xcd * (q + 1) : r * (q + 1) + (xcd - r) * q) + idx;
}

__global__ __launch_bounds__(256) void gemm_k(GemmDesc d0, GemmDesc d1) {
  __shared__ __align__(16) u16 Al[128 * 32];
  __shared__ __align__(16) u16 Wl[128 * 32];
  const int tid = threadIdx.x;
  int wg = blockIdx.x;
  const GemmDesc& d = (wg < d0.nblocks) ? d0 : d1;
  if (wg >= d0.nblocks) wg -= d0.nblocks;
  wg = xcdswz(wg, d.nblocks);
  const int bx = wg % d.NB, by = wg / d.NB;
  const int row0 = by * 128, col0 = bx * 128;
  const int lane = tid & 63, wv = tid >> 6;
  const int wr = wv >> 1, wc = wv & 1;
  const int rowW = wr * 64, colW = wc * 64;
  const int lr = lane & 15, lg4 = lane >> 4;

  // staging: rows of 64B (32 bf16), 4 chunks; swizzle cs = cd ^ ((row>>1)&3)
  const u16* aSrc[2];
  const u16* wSrc[2];
  int aDst[2], wDst[2];
  #pragma unroll
  for (int r = 0; r < 2; ++r) {
    int o = r * 4096 + tid * 16;
    int row = o >> 6, cd = (o >> 4) & 3, cs = cd ^ ((row >> 1) & 3);
    aSrc[r] = d.A + (size_t)(row0 + row) * d.lda + cs * 8;
    wSrc[r] = d.W + (size_t)(col0 + row) * d.ldw + cs * 8;
    aDst[r] = o;
    wDst[r] = o;
  }
  int aOff[4], wOff[4];
  #pragma unroll
  for (int m = 0; m < 4; ++m) {
    int rowi = rowW + m * 16 + lr;
    aOff[m] = rowi * 32 + ((lg4 ^ ((rowi >> 1) & 3)) * 8);
    int rowj = colW + m * 16 + lr;
    wOff[m] = rowj * 32 + ((lg4 ^ ((rowj >> 1) & 3)) * 8);
  }

  f32x4 acc[4][4] = {};
  const int K = d.K;

  for (int k0 = 0; k0 < K; k0 += 32) {
    #pragma unroll
    for (int r = 0; r < 2; ++r) g2l16(aSrc[r] + k0, (char*)Al + aDst[r]);
    #pragma unroll
    for (int r = 0; r < 2; ++r) g2l16(wSrc[r] + k0, (char*)Wl + wDst[r]);
    __syncthreads();
    bfrag af[4], wf[4];
    #pragma unroll
    for (int m = 0; m < 4; ++m) af[m] = *(const bfrag*)(Al + aOff[m]);
    #pragma unroll
    for (int n = 0; n < 4; ++n) wf[n] = *(const bfrag*)(Wl + wOff[n]);
    #pragma unroll
    for (int m = 0; m < 4; ++m)
      #pragma unroll
      for (int n = 0; n < 4; ++n) acc[m][n] = mfma16(af[m], wf[n], acc[m][n]);
    if (k0 + 32 < K) __syncthreads();
  }
  asm volatile("s_nop 7\n\ts_nop 7\n\ts_nop 7");

  #pragma unroll
  for (int m = 0; m < 4; ++m) {
    #pragma unroll
    for (int n = 0; n < 4; ++n) {
      int rb = row0 + rowW + m * 16 + lg4 * 4;
      int c = col0 + colW + n * 16 + lr;
      float bv = d.bias[c];
      if (d.epi == 1) {
        #pragma unroll
        for (int e = 0; e < 4; ++e)
          d.C[(size_t)(rb + e) * d.ldc + c] = f2bf(acc[m][n][e] + bv);
      } else if (d.epi == 2) {
        #pragma unroll
        for (int e = 0; e < 4; ++e)
          d.C[(size_t)(rb + e) * d.ldc + c] = f2bf(gelu_f(acc[m][n][e] + bv));
      } else if (d.epi == 4) {
        if (c < 512) {
          #pragma unroll
          for (int e = 0; e < 4; ++e)
            d.C[(size_t)(rb + e) * 512 + c] = f2bf(acc[m][n][e] + bv);
        } else if (c < 1024) {
          int cl = c - 512;
          int b2 = rb / d.TR, j0 = rb - b2 * d.TR;
          int h2 = cl >> 6, dd = cl & 63;
          ushort4 pk;
          pk.x = f2bf(acc[m][n][0] + bv);
          pk.y = f2bf(acc[m][n][1] + bv);
          pk.z = f2bf(acc[m][n][2] + bv);
          pk.w = f2bf(acc[m][n][3] + bv);
          *(ushort4*)&d.C2[(((size_t)b2 * 8 + h2) * 64 + dd) * d.TR + j0] = pk;
        } else {
          int cl = c - 1024;
          #pragma unroll
          for (int e = 0; e < 4; ++e)
            d.C3[(size_t)(rb + e) * 512 + cl] = f2bf(acc[m][n][e] + bv);
        }
      } else {  // epi == 5
        if (c < 512) {
          #pragma unroll
          for (int e = 0; e < 4; ++e)
            d.C[(size_t)(rb + e) * d.ldc + c] = f2bf(acc[m][n][e] + bv);
        } else {
          int cl = c - 512;
          int b2 = rb / d.TR, j0 = rb - b2 * d.TR;
          int h2 = cl >> 6, dd = cl & 63;
          ushort4 pk;
          pk.x = f2bf(acc[m][n][0] + bv);
          pk.y = f2bf(acc[m][n][1] + bv);
          pk.z = f2bf(acc[m][n][2] + bv);
          pk.w = f2bf(acc[m][n][3] + bv);
          *(ushort4*)&d.C2[(((size_t)b2 * 8 + h2) * 64 + dd) * d.TR + j0] = pk;
        }
      }
    }
  }
}

// =============================== host ===============================
extern "C" void kernel_launch(void* const* d_in, const int* in_sizes, int n_in,
                              void* d_out, int out_size, void* d_ws, size_t ws_size,
                              hipStream_t stream) {
  const float* h_d = (const float*)d_in[0];
  const float* h_p = (const float*)d_in[1];
  const float* gd_w = (const float*)d_in[2];
  const float* gd_b = (const float*)d_in[3];
  const float* gp_w = (const float*)d_in[4];
  const float* gp_b = (const float*)d_in[5];
  const float* wqd_w = (const float*)d_in[6];  const float* wqd_b = (const float*)d_in[7];
  const float* wkp_w = (const float*)d_in[8];  const float* wkp_b = (const float*)d_in[9];
  const float* wvp_w = (const float*)d_in[10]; const float* wvp_b = (const float*)d_in[11];
  const float* wqp_w = (const float*)d_in[12]; const float* wqp_b = (const float*)d_in[13];
  const float* wkd_w = (const float*)d_in[14]; const float* wkd_b = (const float*)d_in[15];
  const float* wvd_w = (const float*)d_in[16]; const float* wvd_b = (const float*)d_in[17];
  const float* od_w = (const float*)d_in[18];  const float* od_b = (const float*)d_in[19];
  const float* op_w = (const float*)d_in[20];  const float* op_b = (const float*)d_in[21];
  const float* fd1_w = (const float*)d_in[22]; const float* fd1_b = (const float*)d_in[23];
  const float* fd2_w = (const float*)d_in[24]; const float* fd2_b = (const float*)d_in[25];
  const float* fp1_w = (const float*)d_in[26]; const float* fp1_b = (const float*)d_in[27];
  const float* fp2_w = (const float*)d_in[28]; const float* fp2_b = (const float*)d_in[29];
  const float* nd1_s = (const float*)d_in[30]; const float* nd1_b = (const float*)d_in[31];
  const float* nd2_s = (const float*)d_in[32]; const float* nd2_b = (const float*)d_in[33];
  const float* np1_s = (const float*)d_in[34]; const float* np1_b = (const float*)d_in[35];
  const float* np2_s = (const float*)d_in[36]; const float* np2_b = (const float*)d_in[37];
  const int* mask_d = (const int*)d_in[38];
  const int* mask_p = (const int*)d_in[39];

  constexpr int B = 16, Ld = 256, Lp = 1024, D = 512, H = 8, F = 2048;
  constexpr int Md = B * Ld;   // 4096
  constexpr int Mp = B * Lp;   // 16384
  constexpr int BH = B * H;    // 128

  char* ws = (char*)d_ws;
  size_t off = 0;
  auto alloc = [&](size_t bytes) {
    size_t o = off;
    off += (bytes + 255) & ~(size_t)255;
    return o;
  };
  auto a16 = [&](size_t els) { return (u16*)(ws + alloc(els * 2)); };
  auto a32 = [&](size_t els) { return (float*)(ws + alloc(els * 4)); };

  u16* w_qd = a16((size_t)D * D);
  u16* w_kp = a16((size_t)D * D);  // w_kp|w_vp|w_qp contiguous (1536 x 512)
  u16* w_vp = a16((size_t)D * D);
  u16* w_qp = a16((size_t)D * D);
  u16* w_kd = a16((size_t)D * D);  // w_kd|w_vd contiguous (1024 x 512)
  u16* w_vd = a16((size_t)D * D);
  u16* w_od = a16((size_t)D * D);
  u16* w_op = a16((size_t)D * D);
  u16* w_fd1 = a16((size_t)F * D);
  u16* w_fd2 = a16((size_t)F * D);
  u16* w_fp1 = a16((size_t)F * D);
  u16* w_fp2 = a16((size_t)F * D);

  u16* hd16 = a16((size_t)Md * D);     // h_d bf16 (pristine; LN1 residual)
  u16* hd2_16 = a16((size_t)Md * D);   // h_d'
  u16* hp16 = a16((size_t)Mp * D);     // h_p bf16 -> h_p' after LN2 (in-place)
  u16* qd16 = a16((size_t)Md * D);     // qd -> attn1 out (in-place) -> kd
  u16* kp16 = a16((size_t)Mp * D);     // kp
  u16* qp16 = a16((size_t)Mp * D);     // qp -> attn2 out (in-place)
  u16* vt16 = a16((size_t)Mp * D);     // vp^T -> vd^T
  u16* obuf16 = a16((size_t)Mp * D);   // op / fp2 outputs
  u16* obuf_d = a16((size_t)Md * D);   // od / fd2 outputs
  u16* t16 = a16((size_t)Mp * F);      // fp1 hidden
  u16* t16d = a16((size_t)Md * F);     // fd1 hidden
  float* logg_d = a32(Md);
  float* logg_p = a32(Mp);
  float* bp3 = a32(1536);
  float* bd2 = a32(1024);

  // --- weight conversions (h_d/h_p conversion fused into gate_k) ---
  {
    CvtArgs a;
    const float* src[12] = {wqd_w, wkp_w, wvp_w, wqp_w, wkd_w, wvd_w,
                            od_w, op_w, fd1_w, fd2_w, fp1_w, fp2_w};
    u16* dst[12] = {w_qd, w_kp, w_vp, w_qp, w_kd, w_vd,
                    w_od, w_op, w_fd1, w_fd2, w_fp1, w_fp2};
    const int nelem[12] = {D * D, D * D, D * D, D * D, D * D, D * D,
                           D * D, D * D, F * D, F * D, F * D, F * D};
    int pfx = 0;
    for (int i = 0; i < 12; ++i) {
      a.s[i] = src[i];
      a.d[i] = dst[i];
      pfx += nelem[i] / 1024;
      a.eb[i] = pfx;
    }
    cvt_all<<<pfx, 256, 0, stream>>>(a);
  }
  biascat_k<<<1, 512, 0, stream>>>(wkp_b, wvp_b, wqp_b, wkd_b, wvd_b, bp3, bd2);

  // --- gates (ORIGINAL fp32 inputs) + bf16 emit of h_d/h_p ---
  gate_k<<<(Md + Mp) / 4, 256, 0, stream>>>(h_d, h_p, gd_w, gd_b, gp_w, gp_b,
                                            logg_d, logg_p, hd16, hp16, Md);

  GemmDesc none = {};

  // --- kvq (from h_p) + qd (from h_d), one launch (both K=512) ---
  {
    GemmDesc kvq = {hp16, w_kp, bp3, kp16, vt16, qp16,
                    D, D, D, D, 1536 / 128, Lp, 4, (Mp / 128) * (1536 / 128)};
    GemmDesc qd = {hd16, w_qd, wqd_b, qd16, nullptr, nullptr,
                   D, D, D, D, D / 128, 0, 1, (Md / 128) * (D / 128)};
    gemm_k<<<kvq.nblocks + qd.nblocks, 256, 0, stream>>>(kvq, qd);
  }

  // --- attn1 (out in-place over qd16) ---
  flash_k<128><<<dim3(Ld / 64, 1, BH), 256, 0, stream>>>(
      qd16, kp16, vt16, logg_p, mask_p, qd16, Ld, Lp, 0.125f);

  // --- o-proj drug ---
  {
    GemmDesc od = {qd16, w_od, od_b, obuf_d, nullptr, nullptr,
                   D, D, D, D, D / 128, 0, 1, (Md / 128) * (D / 128)};
    gemm_k<<<od.nblocks, 256, 0, stream>>>(od, none);
  }
  ln_k<<<Md / 4, 256, 0, stream>>>(hd16, obuf_d, nd1_s, nd1_b, hd2_16);

  // --- kd|vd + fd1, one launch (both K=512) ---
  {
    GemmDesc kdvd = {hd2_16, w_kd, bd2, qd16, vt16, nullptr,
                     D, D, D, D, 1024 / 128, Ld, 5, (Md / 128) * (1024 / 128)};
    GemmDesc fd1 = {hd2_16, w_fd1, fd1_b, t16d, nullptr, nullptr,
                    D, D, D, F, F / 128, 0, 2, (Md / 128) * (F / 128)};
    gemm_k<<<kdvd.nblocks + fd1.nblocks, 256, 0, stream>>>(kdvd, fd1);
  }

  // --- attn2 (out in-place over qp16) ---
  flash_k<128><<<dim3(Lp / 64, 1, BH), 256, 0, stream>>>(
      qp16, qd16, vt16, logg_d, mask_d, qp16, Lp, Ld, 0.125f);

  // --- o-proj protein ---
  {
    GemmDesc op = {qp16, w_op, op_b, obuf16, nullptr, nullptr,
                   D, D, D, D, D / 128, 0, 1, (Mp / 128) * (D / 128)};
    gemm_k<<<op.nblocks, 256, 0, stream>>>(op, none);
  }
  ln_k<<<Mp / 4, 256, 0, stream>>>(hp16, obuf16, np1_s, np1_b, hp16);

  // --- fp1 ALONE (K=512) ---
  {
    GemmDesc fp1 = {hp16, w_fp1, fp1_b, t16, nullptr, nullptr,
                    D, D, D, F, F / 128, 0, 2, (Mp / 128) * (F / 128)};
    gemm_k<<<fp1.nblocks, 256, 0, stream>>>(fp1, none);
  }

  // --- fp2 + fd2 merged (both K=2048, uniform block duration) ---
  {
    GemmDesc fp2 = {t16, w_fp2, fp2_b, obuf16, nullptr, nullptr,
                    F, F, F, D, D / 128, 0, 1, (Mp / 128) * (D / 128)};
    GemmDesc fd2 = {t16d, w_fd2, fd2_b, obuf_d, nullptr, nullptr,
                    F, F, F, D, D / 128, 0, 1, (Md / 128) * (D / 128)};
    gemm_k<<<fp2.nblocks + fd2.nblocks, 256, 0, stream>>>(fp2, fd2);
  }

  // --- merged final LNs -> d_out ---
  lnf_k<<<(Md + Mp) / 4, 256, 0, stream>>>(
      hd2_16, obuf_d, nd2_s, nd2_b, (float*)d_out,
      hp16, obuf16, np2_s, np2_b, (float*)d_out + (size_t)Md * D, Md);
}

// Round 15
// 357.054 us; speedup vs baseline: 1.0493x; 1.0493x over previous
//
#include <hip/hip_runtime.h>

typedef float f32x4 __attribute__((ext_vector_type(4)));
typedef short bfrag __attribute__((ext_vector_type(8)));
typedef short s16x8 __attribute__((ext_vector_type(8)));
typedef unsigned short u16;

__device__ __forceinline__ u16 f2bf(float f) {
  union { float f; unsigned u; } x; x.f = f;
  unsigned r = x.u + 0x7fffu + ((x.u >> 16) & 1u);
  return (u16)(r >> 16);
}
__device__ __forceinline__ float bf2f(u16 v) {
  union { unsigned u; float f; } x; x.u = ((unsigned)v) << 16;
  return x.f;
}

__device__ __forceinline__ void g2l16(const void* g, void* l) {
  void* gnc = const_cast<void*>(g);
  __builtin_amdgcn_global_load_lds((__attribute__((address_space(1))) void*)gnc,
                                   (__attribute__((address_space(3))) void*)l, 16, 0, 0);
}

__device__ __forceinline__ f32x4 mfma16(bfrag a, bfrag b, f32x4 c) {
  asm volatile("v_mfma_f32_16x16x32_bf16 %0, %1, %2, %0" : "+v"(c) : "v"(a), "v"(b));
  return c;
}

__device__ __forceinline__ float wred_sum(float s) {
  #pragma unroll
  for (int o = 32; o; o >>= 1) s += __shfl_xor(s, o);
  return s;
}

__device__ __forceinline__ float gelu_f(float v) {
  return 0.5f * v * (1.f + erff(v * 0.70710678118f));
}

// ---------------- fused f32 -> bf16 convert (12 weight tensors) ----------------
struct CvtArgs {
  const float* s[12];
  u16* d[12];
  int eb[12];
};

__global__ __launch_bounds__(256) void cvt_all(CvtArgs a) {
  const int blk = blockIdx.x;
  int base = 0;
  const float* sp = a.s[0];
  u16* dp = a.d[0];
  #pragma unroll
  for (int i = 0; i < 11; ++i) {
    if (blk >= a.eb[i]) { base = a.eb[i]; sp = a.s[i + 1]; dp = a.d[i + 1]; }
  }
  const size_t gi = ((size_t)(blk - base) * 256 + threadIdx.x) * 4;
  float4 f = *(const float4*)(sp + gi);
  ushort4 o;
  o.x = f2bf(f.x); o.y = f2bf(f.y); o.z = f2bf(f.z); o.w = f2bf(f.w);
  *(ushort4*)(dp + gi) = o;
}

// ---------------- bias concat ----------------
__global__ __launch_bounds__(512) void biascat_k(
    const float* __restrict__ bkp, const float* __restrict__ bvp,
    const float* __restrict__ bqp, const float* __restrict__ bkd,
    const float* __restrict__ bvd, float* __restrict__ bp3,
    float* __restrict__ bd2) {
  int t = threadIdx.x;
  bp3[t] = bkp[t];
  bp3[512 + t] = bvp[t];
  bp3[1024 + t] = bqp[t];
  bd2[t] = bkd[t];
  bd2[512 + t] = bvd[t];
}

// ---------------- uncertainty gates + h -> bf16 emit ----------------
__device__ __forceinline__ float softplus_s(float x) {
  return fmaxf(x, 0.f) + log1pf(expf(-fabsf(x)));
}

__global__ __launch_bounds__(256) void gate_k(
    const float* __restrict__ hd, const float* __restrict__ hp,
    const float* __restrict__ wd, const float* __restrict__ bd,
    const float* __restrict__ wp, const float* __restrict__ bp,
    float* __restrict__ lgd, float* __restrict__ lgp,
    u16* __restrict__ hd16, u16* __restrict__ hp16, int mdTok) {
  const int lane = threadIdx.x & 63, wv = threadIdx.x >> 6;
  size_t tok = (size_t)blockIdx.x * 4 + wv;
  const float* h; const float* w4; const float* b4; float* lg; u16* ho;
  if (tok < (size_t)mdTok) { h = hd; w4 = wd; b4 = bd; lg = lgd; ho = hd16; }
  else { h = hp; w4 = wp; b4 = bp; lg = lgp; ho = hp16; tok -= mdTok; }
  const float* x = h + tok * 512;
  u16* xo = ho + tok * 512;
  float s0 = 0.f, s1 = 0.f, s2 = 0.f, s3 = 0.f;
  #pragma unroll
  for (int i = 0; i < 8; ++i) {
    int c = (i << 6) + lane;
    float xv = x[c];
    xo[c] = f2bf(xv);
    s0 += xv * w4[c];
    s1 += xv * w4[512 + c];
    s2 += xv * w4[1024 + c];
    s3 += xv * w4[1536 + c];
  }
  s0 = wred_sum(s0); s1 = wred_sum(s1); s2 = wred_sum(s2); s3 = wred_sum(s3);
  if (lane == 0) {
    float mu = s0 + b4[0];
    float va = softplus_s(s1 + b4[1]) + 1e-6f;
    float al = softplus_s(s2 + b4[2]) + 1.f + 1e-6f;
    float be = softplus_s(s3 + b4[3]) + 1e-6f;
    float se2 = be / (va * (al - 1.f));
    float g = (1.f / (1.f + expf(-mu))) * expf(-se2);
    g = fminf(fmaxf(g, 1e-3f), 1.f);
    lg[tok] = logf(g + 1e-9f);
  }
}

// ---------------- residual(bf16) + LayerNorm ----------------
__device__ __forceinline__ void ln_body(const u16* res, const u16* y,
                                        const float* sc, const float* bi,
                                        void* outv, int fp32out, size_t row,
                                        int lane) {
  const int c0 = lane * 8;
  float v[8];
  s16x8 yv = *(const s16x8*)(y + row * 512 + c0);
  s16x8 rv = *(const s16x8*)(res + row * 512 + c0);
  float s = 0.f;
  #pragma unroll
  for (int i = 0; i < 8; ++i) {
    v[i] = bf2f((u16)rv[i]) + bf2f((u16)yv[i]);
    s += v[i];
  }
  s = wred_sum(s);
  float m = s * (1.f / 512.f);
  float s2 = 0.f;
  #pragma unroll
  for (int i = 0; i < 8; ++i) { float d = v[i] - m; s2 += d * d; }
  s2 = wred_sum(s2);
  float inv = rsqrtf(s2 * (1.f / 512.f) + 1e-5f);
  float4 sc0 = *(const float4*)(sc + c0), sc1 = *(const float4*)(sc + c0 + 4);
  float4 bi0 = *(const float4*)(bi + c0), bi1 = *(const float4*)(bi + c0 + 4);
  float scv[8] = {sc0.x, sc0.y, sc0.z, sc0.w, sc1.x, sc1.y, sc1.z, sc1.w};
  float biv[8] = {bi0.x, bi0.y, bi0.z, bi0.w, bi1.x, bi1.y, bi1.z, bi1.w};
  float o[8];
  #pragma unroll
  for (int i = 0; i < 8; ++i) o[i] = (v[i] - m) * inv * scv[i] + biv[i];
  if (fp32out) {
    float* of = (float*)outv + row * 512 + c0;
    *(float4*)of = float4{o[0], o[1], o[2], o[3]};
    *(float4*)(of + 4) = float4{o[4], o[5], o[6], o[7]};
  } else {
    s16x8 ov;
    #pragma unroll
    for (int i = 0; i < 8; ++i) ov[i] = (short)f2bf(o[i]);
    *(s16x8*)((u16*)outv + row * 512 + c0) = ov;
  }
}

__global__ __launch_bounds__(256) void ln_k(const u16* __restrict__ res,
                                            const u16* __restrict__ y,
                                            const float* __restrict__ sc,
                                            const float* __restrict__ bi,
                                            u16* __restrict__ out) {
  const int lane = threadIdx.x & 63, w = threadIdx.x >> 6;
  const size_t row = (size_t)blockIdx.x * 4 + w;
  ln_body(res, y, sc, bi, out, 0, row, lane);
}

__global__ __launch_bounds__(256) void lnf_k(
    const u16* __restrict__ rd, const u16* __restrict__ yd,
    const float* __restrict__ scd, const float* __restrict__ bid,
    float* __restrict__ od,
    const u16* __restrict__ rp, const u16* __restrict__ yp,
    const float* __restrict__ scp, const float* __restrict__ bip,
    float* __restrict__ op, int mdRows) {
  const int lane = threadIdx.x & 63, w = threadIdx.x >> 6;
  size_t row = (size_t)blockIdx.x * 4 + w;
  if (row < (size_t)mdRows)
    ln_body(rd, yd, scd, bid, od, 1, row, lane);
  else
    ln_body(rp, yp, scp, bip, op, 1, row - mdRows, lane);
}

// ---------------- fused flash cross-attention (Out may alias Q: per-block disjoint) ----------------
template <int KT>
__global__ __launch_bounds__(256) void flash_k(
    const u16* __restrict__ Q, const u16* __restrict__ Kv,
    const u16* __restrict__ Vt, const float* __restrict__ logg,
    const int* __restrict__ mask, u16* __restrict__ Out,
    int Lq, int Lk, float scale) {
  __shared__ __align__(16) u16 Kl[KT * 64];
  __shared__ __align__(16) u16 Vl[64 * KT];
  __shared__ __align__(16) u16 Pl[64 * (KT + 8)];
  const int tid = threadIdx.x;
  const int lane = tid & 63, wv = tid >> 6;
  const int lr = lane & 15, lg4 = lane >> 4;
  const int bh = blockIdx.z;
  const int b = bh >> 3, h = bh & 7;
  const int q0 = blockIdx.x * 64;

  bfrag af[2];
  {
    const u16* qrow = Q + (size_t)(b * Lq + q0 + wv * 16 + lr) * 512 + h * 64;
    af[0] = *(const bfrag*)(qrow + lg4 * 8);
    af[1] = *(const bfrag*)(qrow + 32 + lg4 * 8);
  }
  float mreg[4] = {-3e38f, -3e38f, -3e38f, -3e38f};
  float lreg[4] = {0.f, 0.f, 0.f, 0.f};
  f32x4 Oa[4] = {};
  const float* lgb = logg + (size_t)b * Lk;
  const int* mkb = mask + (size_t)b * Lk;

  const int NKT = Lk / KT;
  for (int t = 0; t < NKT; ++t) {
    const int k0 = t * KT;
    __syncthreads();
    {
      const char* kb = (const char*)(Kv + (size_t)(b * Lk + k0) * 512 + h * 64);
      #pragma unroll
      for (int r = 0; r < KT / 32; ++r) {
        int o = r * 4096 + tid * 16;
        int rr = o >> 7, cd = (o >> 4) & 7;
        int cs = cd ^ (rr & 7);
        g2l16(kb + (size_t)rr * 1024 + cs * 16, (char*)Kl + o);
      }
      const char* vb = (const char*)(Vt + (size_t)bh * 64 * Lk + k0);
      #pragma unroll
      for (int r = 0; r < KT / 32; ++r) {
        int o = r * 4096 + tid * 16;
        int rr = o >> 8, cd = (o >> 4) & 15;
        int cs = (cd & 8) | ((cd & 7) ^ (rr & 7));
        g2l16(vb + (size_t)rr * (Lk * 2) + cs * 16, (char*)Vl + o);
      }
    }
    __syncthreads();

    f32x4 sa[KT / 16];
    #pragma unroll
    for (int n = 0; n < KT / 16; ++n) {
      sa[n] = f32x4{0.f, 0.f, 0.f, 0.f};
      int row = n * 16 + lr;
      #pragma unroll
      for (int ks = 0; ks < 2; ++ks) {
        bfrag kf = *(const bfrag*)(Kl + row * 64 + (((ks * 4 + lg4) ^ (row & 7)) * 8));
        sa[n] = mfma16(af[ks], kf, sa[n]);
      }
    }
    asm volatile("s_nop 7\n\ts_nop 7");

    float pv[KT / 16][4];
    float nm[4] = {-3e38f, -3e38f, -3e38f, -3e38f};
    #pragma unroll
    for (int n = 0; n < KT / 16; ++n) {
      int kk = k0 + n * 16 + lr;
      float lgv = lgb[kk];
      int mkv = mkb[kk];
      #pragma unroll
      for (int e = 0; e < 4; ++e) {
        float tv = mkv ? fmaf(sa[n][e], scale, lgv) : -1e9f;
        pv[n][e] = tv;
        nm[e] = fmaxf(nm[e], tv);
      }
    }
    float fac[4], rs[4];
    #pragma unroll
    for (int e = 0; e < 4; ++e) {
      nm[e] = fmaxf(nm[e], __shfl_xor(nm[e], 1));
      nm[e] = fmaxf(nm[e], __shfl_xor(nm[e], 2));
      nm[e] = fmaxf(nm[e], __shfl_xor(nm[e], 4));
      nm[e] = fmaxf(nm[e], __shfl_xor(nm[e], 8));
      nm[e] = fmaxf(nm[e], mreg[e]);
      fac[e] = __expf(mreg[e] - nm[e]);
      mreg[e] = nm[e];
      rs[e] = 0.f;
    }
    #pragma unroll
    for (int n = 0; n < KT / 16; ++n)
      #pragma unroll
      for (int e = 0; e < 4; ++e) {
        float p = __expf(pv[n][e] - nm[e]);
        pv[n][e] = p;
        rs[e] += p;
      }
    #pragma unroll
    for (int e = 0; e < 4; ++e) {
      rs[e] += __shfl_xor(rs[e], 1);
      rs[e] += __shfl_xor(rs[e], 2);
      rs[e] += __shfl_xor(rs[e], 4);
      rs[e] += __shfl_xor(rs[e], 8);
      lreg[e] = lreg[e] * fac[e] + rs[e];
    }
    #pragma unroll
    for (int n2 = 0; n2 < 4; ++n2)
      #pragma unroll
      for (int e = 0; e < 4; ++e) Oa[n2][e] *= fac[e];

    {
      int prow = wv * 16 + lg4 * 4;
      #pragma unroll
      for (int n = 0; n < KT / 16; ++n)
        #pragma unroll
        for (int e = 0; e < 4; ++e)
          Pl[(prow + e) * (KT + 8) + n * 16 + lr] = f2bf(pv[n][e]);
    }
    #pragma unroll
    for (int ks = 0; ks < KT / 32; ++ks) {
      bfrag pf = *(const bfrag*)(Pl + (wv * 16 + lr) * (KT + 8) + (ks * 4 + lg4) * 8);
      #pragma unroll
      for (int n2 = 0; n2 < 4; ++n2) {
        int vrow = n2 * 16 + lr;
        int ch = ks * 4 + lg4;
        int chs = (ch & 8) | ((ch & 7) ^ (vrow & 7));
        bfrag vf = *(const bfrag*)(Vl + vrow * KT + chs * 8);
        Oa[n2] = mfma16(pf, vf, Oa[n2]);
      }
    }
  }
  asm volatile("s_nop 7\n\ts_nop 7");

  float inv[4];
  #pragma unroll
  for (int e = 0; e < 4; ++e) inv[e] = 1.f / lreg[e];
  u16* ob = Out + (size_t)(b * Lq + q0 + wv * 16 + lg4 * 4) * 512 + h * 64;
  #pragma unroll
  for (int n2 = 0; n2 < 4; ++n2)
    #pragma unroll
    for (int e = 0; e < 4; ++e)
      ob[(size_t)e * 512 + n2 * 16 + lr] = f2bf(Oa[n2][e] * inv[e]);
}

// ---------------- 2-barrier 128x128/BK=64 MFMA GEMM, 2-descriptor (R13 final) ----------------
// Descriptor select on raw blockIdx, THEN per-descriptor bijective XCD swizzle.
// Merges only combine SAME-K descriptors (uniform block duration).
// epi: 1=bf16, 2=gelu->bf16,
//      4=kvq concat: c<512 -> C (ld512); c<1024 -> V^T C2 (TR); else C3 (ld512)
//      5=kd|vd concat: c<512 -> C; else V^T -> C2
struct GemmDesc {
  const u16* A;
  const u16* W;
  const float* bias;
  u16 *C, *C2, *C3;
  int K, lda, ldw, ldc, NB, TR, epi, nblocks;
};

__device__ __forceinline__ int xcdswz(int wg, int nb) {
  int xcd = wg & 7, idx = wg >> 3, q = nb >> 3, r = nb & 7;
  return (xcd < r ? xcd * (q + 1) : r * (q + 1) + (xcd - r) * q) + idx;
}

__global__ __launch_bounds__(256) void gemm_k(GemmDesc d0, GemmDesc d1) {
  __shared__ __align__(16) u16 Al[128 * 64];
  __shared__ __align__(16) u16 Wl[128 * 64];
  const int tid = threadIdx.x;
  int wg = blockIdx.x;
  const GemmDesc& d = (wg < d0.nblocks) ? d0 : d1;
  if (wg >= d0.nblocks) wg -= d0.nblocks;
  wg = xcdswz(wg, d.nblocks);
  const int bx = wg % d.NB, by = wg / d.NB;
  const int row0 = by * 128, col0 = bx * 128;
  const int lane = tid & 63, wv = tid >> 6;
  const int wr = wv >> 1, wc = wv & 1;
  const int rowW = wr * 64, colW = wc * 64;
  const int lr = lane & 15, lg4 = lane >> 4;

  const u16* aSrc[4];
  const u16* wSrc[4];
  int aDst[4], wDst[4];
  #pragma unroll
  for (int r = 0; r < 4; ++r) {
    int o = r * 4096 + tid * 16;
    int row = o >> 7, cd = (o >> 4) & 7, cs = cd ^ (row & 7);
    aSrc[r] = d.A + (size_t)(row0 + row) * d.lda + cs * 8;
    wSrc[r] = d.W + (size_t)(col0 + row) * d.ldw + cs * 8;
    aDst[r] = o;
    wDst[r] = o;
  }
  int aOff[4][2], wOff[4][2];
  #pragma unroll
  for (int m = 0; m < 4; ++m) {
    int rowi = rowW + m * 16 + lr;
    int rowj = colW + m * 16 + lr;
    #pragma unroll
    for (int ks = 0; ks < 2; ++ks) {
      aOff[m][ks] = rowi * 64 + (((ks * 4 + lg4) ^ (rowi & 7)) * 8);
      wOff[m][ks] = rowj * 64 + (((ks * 4 + lg4) ^ (rowj & 7)) * 8);
    }
  }

  f32x4 acc[4][4] = {};
  const int K = d.K;

  for (int k0 = 0; k0 < K; k0 += 64) {
    #pragma unroll
    for (int r = 0; r < 4; ++r) g2l16(aSrc[r] + k0, (char*)Al + aDst[r]);
    #pragma unroll
    for (int r = 0; r < 4; ++r) g2l16(wSrc[r] + k0, (char*)Wl + wDst[r]);
    __syncthreads();
    #pragma unroll
    for (int ks = 0; ks < 2; ++ks) {
      bfrag af[4], wf[4];
      #pragma unroll
      for (int m = 0; m < 4; ++m) af[m] = *(const bfrag*)(Al + aOff[m][ks]);
      #pragma unroll
      for (int n = 0; n < 4; ++n) wf[n] = *(const bfrag*)(Wl + wOff[n][ks]);
      #pragma unroll
      for (int m = 0; m < 4; ++m)
        #pragma unroll
        for (int n = 0; n < 4; ++n) acc[m][n] = mfma16(af[m], wf[n], acc[m][n]);
    }
    if (k0 + 64 < K) __syncthreads();
  }
  asm volatile("s_nop 7\n\ts_nop 7\n\ts_nop 7");

  #pragma unroll
  for (int m = 0; m < 4; ++m) {
    #pragma unroll
    for (int n = 0; n < 4; ++n) {
      int rb = row0 + rowW + m * 16 + lg4 * 4;
      int c = col0 + colW + n * 16 + lr;
      float bv = d.bias[c];
      if (d.epi == 1) {
        #pragma unroll
        for (int e = 0; e < 4; ++e)
          d.C[(size_t)(rb + e) * d.ldc + c] = f2bf(acc[m][n][e] + bv);
      } else if (d.epi == 2) {
        #pragma unroll
        for (int e = 0; e < 4; ++e)
          d.C[(size_t)(rb + e) * d.ldc + c] = f2bf(gelu_f(acc[m][n][e] + bv));
      } else if (d.epi == 4) {
        if (c < 512) {
          #pragma unroll
          for (int e = 0; e < 4; ++e)
            d.C[(size_t)(rb + e) * 512 + c] = f2bf(acc[m][n][e] + bv);
        } else if (c < 1024) {
          int cl = c - 512;
          int b2 = rb / d.TR, j0 = rb - b2 * d.TR;
          int h2 = cl >> 6, dd = cl & 63;
          ushort4 pk;
          pk.x = f2bf(acc[m][n][0] + bv);
          pk.y = f2bf(acc[m][n][1] + bv);
          pk.z = f2bf(acc[m][n][2] + bv);
          pk.w = f2bf(acc[m][n][3] + bv);
          *(ushort4*)&d.C2[(((size_t)b2 * 8 + h2) * 64 + dd) * d.TR + j0] = pk;
        } else {
          int cl = c - 1024;
          #pragma unroll
          for (int e = 0; e < 4; ++e)
            d.C3[(size_t)(rb + e) * 512 + cl] = f2bf(acc[m][n][e] + bv);
        }
      } else {  // epi == 5
        if (c < 512) {
          #pragma unroll
          for (int e = 0; e < 4; ++e)
            d.C[(size_t)(rb + e) * d.ldc + c] = f2bf(acc[m][n][e] + bv);
        } else {
          int cl = c - 512;
          int b2 = rb / d.TR, j0 = rb - b2 * d.TR;
          int h2 = cl >> 6, dd = cl & 63;
          ushort4 pk;
          pk.x = f2bf(acc[m][n][0] + bv);
          pk.y = f2bf(acc[m][n][1] + bv);
          pk.z = f2bf(acc[m][n][2] + bv);
          pk.w = f2bf(acc[m][n][3] + bv);
          *(ushort4*)&d.C2[(((size_t)b2 * 8 + h2) * 64 + dd) * d.TR + j0] = pk;
        }
      }
    }
  }
}

// =============================== host ===============================
extern "C" void kernel_launch(void* const* d_in, const int* in_sizes, int n_in,
                              void* d_out, int out_size, void* d_ws, size_t ws_size,
                              hipStream_t stream) {
  const float* h_d = (const float*)d_in[0];
  const float* h_p = (const float*)d_in[1];
  const float* gd_w = (const float*)d_in[2];
  const float* gd_b = (const float*)d_in[3];
  const float* gp_w = (const float*)d_in[4];
  const float* gp_b = (const float*)d_in[5];
  const float* wqd_w = (const float*)d_in[6];  const float* wqd_b = (const float*)d_in[7];
  const float* wkp_w = (const float*)d_in[8];  const float* wkp_b = (const float*)d_in[9];
  const float* wvp_w = (const float*)d_in[10]; const float* wvp_b = (const float*)d_in[11];
  const float* wqp_w = (const float*)d_in[12]; const float* wqp_b = (const float*)d_in[13];
  const float* wkd_w = (const float*)d_in[14]; const float* wkd_b = (const float*)d_in[15];
  const float* wvd_w = (const float*)d_in[16]; const float* wvd_b = (const float*)d_in[17];
  const float* od_w = (const float*)d_in[18];  const float* od_b = (const float*)d_in[19];
  const float* op_w = (const float*)d_in[20];  const float* op_b = (const float*)d_in[21];
  const float* fd1_w = (const float*)d_in[22]; const float* fd1_b = (const float*)d_in[23];
  const float* fd2_w = (const float*)d_in[24]; const float* fd2_b = (const float*)d_in[25];
  const float* fp1_w = (const float*)d_in[26]; const float* fp1_b = (const float*)d_in[27];
  const float* fp2_w = (const float*)d_in[28]; const float* fp2_b = (const float*)d_in[29];
  const float* nd1_s = (const float*)d_in[30]; const float* nd1_b = (const float*)d_in[31];
  const float* nd2_s = (const float*)d_in[32]; const float* nd2_b = (const float*)d_in[33];
  const float* np1_s = (const float*)d_in[34]; const float* np1_b = (const float*)d_in[35];
  const float* np2_s = (const float*)d_in[36]; const float* np2_b = (const float*)d_in[37];
  const int* mask_d = (const int*)d_in[38];
  const int* mask_p = (const int*)d_in[39];

  constexpr int B = 16, Ld = 256, Lp = 1024, D = 512, H = 8, F = 2048;
  constexpr int Md = B * Ld;   // 4096
  constexpr int Mp = B * Lp;   // 16384
  constexpr int BH = B * H;    // 128

  char* ws = (char*)d_ws;
  size_t off = 0;
  auto alloc = [&](size_t bytes) {
    size_t o = off;
    off += (bytes + 255) & ~(size_t)255;
    return o;
  };
  auto a16 = [&](size_t els) { return (u16*)(ws + alloc(els * 2)); };
  auto a32 = [&](size_t els) { return (float*)(ws + alloc(els * 4)); };

  u16* w_qd = a16((size_t)D * D);
  u16* w_kp = a16((size_t)D * D);  // w_kp|w_vp|w_qp contiguous (1536 x 512)
  u16* w_vp = a16((size_t)D * D);
  u16* w_qp = a16((size_t)D * D);
  u16* w_kd = a16((size_t)D * D);  // w_kd|w_vd contiguous (1024 x 512)
  u16* w_vd = a16((size_t)D * D);
  u16* w_od = a16((size_t)D * D);
  u16* w_op = a16((size_t)D * D);
  u16* w_fd1 = a16((size_t)F * D);
  u16* w_fd2 = a16((size_t)F * D);
  u16* w_fp1 = a16((size_t)F * D);
  u16* w_fp2 = a16((size_t)F * D);

  u16* hd16 = a16((size_t)Md * D);     // h_d bf16 (pristine; LN1 residual)
  u16* hd2_16 = a16((size_t)Md * D);   // h_d'
  u16* hp16 = a16((size_t)Mp * D);     // h_p bf16 -> h_p' after LN2 (in-place)
  u16* qd16 = a16((size_t)Md * D);     // qd -> attn1 out (in-place) -> kd
  u16* kp16 = a16((size_t)Mp * D);     // kp
  u16* qp16 = a16((size_t)Mp * D);     // qp -> attn2 out (in-place)
  u16* vt16 = a16((size_t)Mp * D);     // vp^T -> vd^T
  u16* obuf16 = a16((size_t)Mp * D);   // op / fp2 outputs
  u16* obuf_d = a16((size_t)Md * D);   // od / fd2 outputs
  u16* t16 = a16((size_t)Mp * F);      // fp1 hidden
  u16* t16d = a16((size_t)Md * F);     // fd1 hidden
  float* logg_d = a32(Md);
  float* logg_p = a32(Mp);
  float* bp3 = a32(1536);
  float* bd2 = a32(1024);

  // --- weight conversions (h_d/h_p conversion fused into gate_k) ---
  {
    CvtArgs a;
    const float* src[12] = {wqd_w, wkp_w, wvp_w, wqp_w, wkd_w, wvd_w,
                            od_w, op_w, fd1_w, fd2_w, fp1_w, fp2_w};
    u16* dst[12] = {w_qd, w_kp, w_vp, w_qp, w_kd, w_vd,
                    w_od, w_op, w_fd1, w_fd2, w_fp1, w_fp2};
    const int nelem[12] = {D * D, D * D, D * D, D * D, D * D, D * D,
                           D * D, D * D, F * D, F * D, F * D, F * D};
    int pfx = 0;
    for (int i = 0; i < 12; ++i) {
      a.s[i] = src[i];
      a.d[i] = dst[i];
      pfx += nelem[i] / 1024;
      a.eb[i] = pfx;
    }
    cvt_all<<<pfx, 256, 0, stream>>>(a);
  }
  biascat_k<<<1, 512, 0, stream>>>(wkp_b, wvp_b, wqp_b, wkd_b, wvd_b, bp3, bd2);

  // --- gates (ORIGINAL fp32 inputs) + bf16 emit of h_d/h_p ---
  gate_k<<<(Md + Mp) / 4, 256, 0, stream>>>(h_d, h_p, gd_w, gd_b, gp_w, gp_b,
                                            logg_d, logg_p, hd16, hp16, Md);

  GemmDesc none = {};

  // --- kvq (from h_p) + qd (from h_d), one launch (both K=512) ---
  {
    GemmDesc kvq = {hp16, w_kp, bp3, kp16, vt16, qp16,
                    D, D, D, D, 1536 / 128, Lp, 4, (Mp / 128) * (1536 / 128)};
    GemmDesc qd = {hd16, w_qd, wqd_b, qd16, nullptr, nullptr,
                   D, D, D, D, D / 128, 0, 1, (Md / 128) * (D / 128)};
    gemm_k<<<kvq.nblocks + qd.nblocks, 256, 0, stream>>>(kvq, qd);
  }

  // --- attn1 (out in-place over qd16) ---
  flash_k<128><<<dim3(Ld / 64, 1, BH), 256, 0, stream>>>(
      qd16, kp16, vt16, logg_p, mask_p, qd16, Ld, Lp, 0.125f);

  // --- o-proj drug ---
  {
    GemmDesc od = {qd16, w_od, od_b, obuf_d, nullptr, nullptr,
                   D, D, D, D, D / 128, 0, 1, (Md / 128) * (D / 128)};
    gemm_k<<<od.nblocks, 256, 0, stream>>>(od, none);
  }
  ln_k<<<Md / 4, 256, 0, stream>>>(hd16, obuf_d, nd1_s, nd1_b, hd2_16);

  // --- kd|vd + fd1, one launch (both K=512) ---
  {
    GemmDesc kdvd = {hd2_16, w_kd, bd2, qd16, vt16, nullptr,
                     D, D, D, D, 1024 / 128, Ld, 5, (Md / 128) * (1024 / 128)};
    GemmDesc fd1 = {hd2_16, w_fd1, fd1_b, t16d, nullptr, nullptr,
                    D, D, D, F, F / 128, 0, 2, (Md / 128) * (F / 128)};
    gemm_k<<<kdvd.nblocks + fd1.nblocks, 256, 0, stream>>>(kdvd, fd1);
  }

  // --- attn2 (out in-place over qp16) ---
  flash_k<128><<<dim3(Lp / 64, 1, BH), 256, 0, stream>>>(
      qp16, qd16, vt16, logg_d, mask_d, qp16, Lp, Ld, 0.125f);

  // --- o-proj protein ---
  {
    GemmDesc op = {qp16, w_op, op_b, obuf16, nullptr, nullptr,
                   D, D, D, D, D / 128, 0, 1, (Mp / 128) * (D / 128)};
    gemm_k<<<op.nblocks, 256, 0, stream>>>(op, none);
  }
  ln_k<<<Mp / 4, 256, 0, stream>>>(hp16, obuf16, np1_s, np1_b, hp16);

  // --- fp1 ALONE (K=512; mixed-K merge with fd2 measured -40%) ---
  {
    GemmDesc fp1 = {hp16, w_fp1, fp1_b, t16, nullptr, nullptr,
                    D, D, D, F, F / 128, 0, 2, (Mp / 128) * (F / 128)};
    gemm_k<<<fp1.nblocks, 256, 0, stream>>>(fp1, none);
  }

  // --- fp2 + fd2 merged (both K=2048, uniform block duration) ---
  {
    GemmDesc fp2 = {t16, w_fp2, fp2_b, obuf16, nullptr, nullptr,
                    F, F, F, D, D / 128, 0, 1, (Mp / 128) * (D / 128)};
    GemmDesc fd2 = {t16d, w_fd2, fd2_b, obuf_d, nullptr, nullptr,
                    F, F, F, D, D / 128, 0, 1, (Md / 128) * (D / 128)};
    gemm_k<<<fp2.nblocks + fd2.nblocks, 256, 0, stream>>>(fp2, fd2);
  }

  // --- merged final LNs -> d_out ---
  lnf_k<<<(Md + Mp) / 4, 256, 0, stream>>>(
      hd2_16, obuf_d, nd2_s, nd2_b, (float*)d_out,
      hp16, obuf16, np2_s, np2_b, (float*)d_out + (size_t)Md * D, Md);
}